// Round 4
// baseline (58.987 us; speedup 1.0000x reference)
//
#include <hip/hip_runtime.h>

typedef __attribute__((ext_vector_type(8))) short bf16x8;
typedef __attribute__((ext_vector_type(4))) float f32x4;

#define EPS 1e-5f

// ws layout: frag blocks (182 x 1KB bf16) then fp32 ST region
#define N_FRAG_BLOCKS 182
#define WSB_LEAF 0      // 64 blocks: leaf l
#define WSB_MID  64     // 80 blocks: (m*2+t)*5 + s
#define WSB_ROOT 144    // 36 blocks: t*9 + s
#define WSB_HEAD 180    // 2 blocks: s
#define ST_SL 0
#define ST_TL 1024
#define ST_SM 2048
#define ST_TM 2304
#define ST_SR 2560
#define ST_TR 2624
#define WS_ST_BYTE_OFF (N_FRAG_BLOCKS * 1024)

__device__ __forceinline__ unsigned short f2bf(float f) {  // RNE float->bf16
    unsigned u = __float_as_uint(f);
    unsigned r = u + 0x7fffu + ((u >> 16) & 1u);
    return (unsigned short)(r >> 16);
}

__device__ __forceinline__ unsigned pack2bf(float a, float b) {
    return (unsigned)f2bf(a) | ((unsigned)f2bf(b) << 16);
}

__device__ __forceinline__ bf16x8 pack8(float4 a, float4 b) {
    union { unsigned u[4]; bf16x8 v; } r;
    r.u[0] = pack2bf(a.x, a.y); r.u[1] = pack2bf(a.z, a.w);
    r.u[2] = pack2bf(b.x, b.y); r.u[3] = pack2bf(b.z, b.w);
    return r.v;
}

__device__ __forceinline__ float tanh_fast(float x) {
    float e = __expf(2.0f * x);
    return 1.0f - 2.0f / (e + 1.0f);
}

// ---------------- prep: fragment-ordered bf16 weights + folded BN ----------
__global__ void ontology_prep(
    const float* __restrict__ Wl, const float* __restrict__ Wm,
    const float* __restrict__ Wr, const float* __restrict__ Wh,
    const float* __restrict__ bl, const float* __restrict__ gl,
    const float* __restrict__ betal, const float* __restrict__ ml,
    const float* __restrict__ vl,
    const float* __restrict__ bm, const float* __restrict__ gm,
    const float* __restrict__ betam, const float* __restrict__ mm,
    const float* __restrict__ vm,
    const float* __restrict__ br, const float* __restrict__ gr,
    const float* __restrict__ betar, const float* __restrict__ mr,
    const float* __restrict__ vr,
    unsigned short* __restrict__ wsFrag, float* __restrict__ wsST)
{
    const int b = blockIdx.x;
    const int t = threadIdx.x;
    if (b < N_FRAG_BLOCKS) {
        // A'-frag layout (transposed weights): lane t holds A'[row=t&15][k=(t>>4)*8+i]
        const int row = t & 15, g = t >> 4;
        unsigned short vals[8];
        #pragma unroll
        for (int i = 0; i < 8; ++i) {
            const int k = g * 8 + i;
            float v = 0.f;
            if (b < 64) {                       // leaf l: pair-packed K
                const int l = b;
                if ((l & 1) == 0) { if (k < 16)  v = Wl[l * 256 + k * 16 + row]; }
                else              { if (k >= 16) v = Wl[l * 256 + (k - 16) * 16 + row]; }
            } else if (b < 144) {               // mid
                const int idx = b - 64, m = idx / 10, rem = idx % 10;
                const int tt = rem / 5, s = rem % 5;
                const int krow = s * 32 + k;
                if (krow < 144) v = Wm[m * 4608 + krow * 32 + tt * 16 + row];
            } else if (b < 180) {               // root
                const int idx = b - 144, tt = idx / 9, s = idx % 9;
                if (s == 0) { if (k < 16) v = Wr[k * 64 + tt * 16 + row]; }
                else { const int krow = 16 + (s - 1) * 32 + k;
                       v = Wr[krow * 64 + tt * 16 + row]; }
            } else {                            // head
                const int s = b - 180, krow = s * 32 + k;
                if (row < 10) v = Wh[krow * 10 + row];
            }
            vals[i] = f2bf(v);
        }
        #pragma unroll
        for (int i = 0; i < 8; ++i) wsFrag[b * 512 + t * 8 + i] = vals[i];
    } else if (b == N_FRAG_BLOCKS) {            // leaf ST (1024)
        for (int i = 0; i < 16; ++i) {
            const int id = t + 64 * i;
            const float S = gl[id] * rsqrtf(vl[id] + EPS);
            wsST[ST_SL + id] = S;
            wsST[ST_TL + id] = (bl[id] - ml[id]) * S + betal[id];
        }
    } else if (b == N_FRAG_BLOCKS + 1) {        // mid ST (256)
        for (int i = 0; i < 4; ++i) {
            const int id = t + 64 * i;
            const float S = gm[id] * rsqrtf(vm[id] + EPS);
            wsST[ST_SM + id] = S;
            wsST[ST_TM + id] = (bm[id] - mm[id]) * S + betam[id];
        }
    } else {                                     // root ST (64)
        const int id = t;
        const float S = gr[id] * rsqrtf(vr[id] + EPS);
        wsST[ST_SR + id] = S;
        wsST[ST_TR + id] = (br[id] - mr[id]) * S + betar[id];
    }
}

// ---------------- main fused MFMA kernel, 1 wave / 16 samples --------------
// Wave walks 8 mids; x staged ahead via global_load_lds (triple buffer,
// lookahead 2, counted vmcnt). Zero barriers (all LDS deps intra-wave).
// Root accumulated per-phase from 32-col hm slab; lane = (c=sample, g).
__global__ __launch_bounds__(64, 2) void ontology_mfma(
    const float* __restrict__ x,
    const unsigned short* __restrict__ wsFrag,
    const float* __restrict__ wsST,
    const float* __restrict__ bh,
    float* __restrict__ out)
{
    // xs rows: 148 floats (592B = 37*16, 16B-aligned, 2-way bank alias = free)
    // buffer padded to 2560 floats = 10 KiB = exactly 10 gl_lds instrs.
    __shared__ __align__(16) float xs[3][2560];
    __shared__ __align__(16) unsigned short mid_in[16][168];  // K=160 B-data + pad
    __shared__ __align__(16) unsigned short hm[16][40];       // current mid's 32 cols
    __shared__ __align__(16) unsigned short hr[16][72];       // root outs (64 cols)

    const int lane = threadIdx.x;
    const int c = lane & 15;        // sample within tile
    const int g = lane >> 4;        // k/feat group
    const int rowbase = blockIdx.x * 16;
    const float* xrow = x + (size_t)(rowbase + c) * 1168;

    const float* Sl = wsST + ST_SL; const float* Tl = wsST + ST_TL;
    const float* Sm = wsST + ST_SM; const float* Tm = wsST + ST_TM;
    const float* Sr = wsST + ST_SR; const float* Tr = wsST + ST_TR;

    // stage mid's x region (xm 16 floats + leaves 128) into xs[b]
    auto stage = [&](int mid, int b) {
        float* dst = &xs[b][0];
        #pragma unroll
        for (int k = 0; k < 10; ++k) {
            const int fo = k * 256 + lane * 4;      // float idx in buffer
            const int row = fo / 148;
            const int col = fo - row * 148;
            const float* src;
            if ((row < 16) & (col < 144)) {
                const float* xr = x + (size_t)(rowbase + row) * 1168;
                src = (col < 16) ? (xr + 1024 + mid * 16 + col)
                                 : (xr + (mid * 128 - 16) + col);
            } else {
                src = xrow;                          // dummy (L1-hit, harmless)
            }
            __builtin_amdgcn_global_load_lds(
                (const __attribute__((address_space(1))) unsigned int*)src,
                (__attribute__((address_space(3))) unsigned int*)(dst + k * 256),
                16, 0, 0);
        }
    };

    stage(0, 0);
    stage(1, 1);

    // zero pad-K cols 144..159 of mid_in (written once)
    {
        uint2 z; z.x = 0u; z.y = 0u;
        *(uint2*)&mid_in[c][144 + 4 * g] = z;
    }

    // root accumulators; K-step s=0 from x[1152..1168] (A rows k>=16 are 0)
    f32x4 accR[4];
    {
        const float* xp = xrow + 1152 + (g & 1) * 8;
        float4 xa = *(const float4*)xp;
        float4 xb = *(const float4*)(xp + 4);
        bf16x8 bfrag = pack8(xa, xb);
        #pragma unroll
        for (int t = 0; t < 4; ++t) {
            bf16x8 a = *(const bf16x8*)(wsFrag + (WSB_ROOT + t * 9) * 512 + lane * 8);
            f32x4 zz = {0.f, 0.f, 0.f, 0.f};
            accR[t] = __builtin_amdgcn_mfma_f32_16x16x32_bf16(a, bfrag, zz, 0, 0, 0);
        }
    }

    #pragma unroll 1
    for (int mi = 0; mi < 8; ++mi) {
        const int b = mi % 3;
        // wait for stage(mi): in-order vmcnt retirement => last-10 outstanding
        // are always the newest stage (S_{mi+1}); everything older is done.
        if (mi < 7) { asm volatile("s_waitcnt vmcnt(10)" ::: "memory"); }
        else        { asm volatile("s_waitcnt vmcnt(0)" ::: "memory"); }
        const float* xb_ = &xs[b][0];

        // xm (cols 0..15) -> mid_in
        {
            float4 xm4 = *(const float4*)(xb_ + c * 148 + 4 * g);
            uint2 pm; pm.x = pack2bf(xm4.x, xm4.y); pm.y = pack2bf(xm4.z, xm4.w);
            *(uint2*)&mid_in[c][4 * g] = pm;
        }
        // 4 leaf-pairs -> 8 leaves, outputs into mid_in cols 16..143
        #pragma unroll
        for (int p = 0; p < 4; ++p) {
            const float* xp = xb_ + c * 148 + 16 + p * 32 + g * 8;
            float4 xa = *(const float4*)xp;
            float4 x2 = *(const float4*)(xp + 4);
            bf16x8 bfrag = pack8(xa, x2);
            #pragma unroll
            for (int e = 0; e < 2; ++e) {
                const int leaf = mi * 8 + p * 2 + e;
                bf16x8 afrag = *(const bf16x8*)(wsFrag + (WSB_LEAF + leaf) * 512 + lane * 8);
                f32x4 zz = {0.f, 0.f, 0.f, 0.f};
                f32x4 acc = __builtin_amdgcn_mfma_f32_16x16x32_bf16(afrag, bfrag, zz, 0, 0, 0);
                float4 S = *(const float4*)(Sl + leaf * 16 + 4 * g);
                float4 T = *(const float4*)(Tl + leaf * 16 + 4 * g);
                float h0 = tanh_fast(acc[0] * S.x + T.x);
                float h1 = tanh_fast(acc[1] * S.y + T.y);
                float h2 = tanh_fast(acc[2] * S.z + T.z);
                float h3 = tanh_fast(acc[3] * S.w + T.w);
                uint2 pk; pk.x = pack2bf(h0, h1); pk.y = pack2bf(h2, h3);
                *(uint2*)&mid_in[c][16 + (p * 2 + e) * 16 + 4 * g] = pk;
            }
        }
        // mid mi: 2 col-tiles x 5 K-steps
        {
            f32x4 acc0 = {0.f, 0.f, 0.f, 0.f};
            f32x4 acc1 = {0.f, 0.f, 0.f, 0.f};
            const unsigned short* fb = wsFrag + (WSB_MID + mi * 10) * 512 + lane * 8;
            #pragma unroll
            for (int s = 0; s < 5; ++s) {
                bf16x8 bfrag = *(const bf16x8*)&mid_in[c][s * 32 + g * 8];
                bf16x8 a0 = *(const bf16x8*)(fb + s * 512);
                bf16x8 a1 = *(const bf16x8*)(fb + (5 + s) * 512);
                acc0 = __builtin_amdgcn_mfma_f32_16x16x32_bf16(a0, bfrag, acc0, 0, 0, 0);
                acc1 = __builtin_amdgcn_mfma_f32_16x16x32_bf16(a1, bfrag, acc1, 0, 0, 0);
            }
            #pragma unroll
            for (int t = 0; t < 2; ++t) {
                f32x4 acc = t ? acc1 : acc0;
                const int po = mi * 32 + t * 16 + 4 * g;
                float4 S = *(const float4*)(Sm + po);
                float4 T = *(const float4*)(Tm + po);
                float h0 = tanh_fast(acc[0] * S.x + T.x);
                float h1 = tanh_fast(acc[1] * S.y + T.y);
                float h2 = tanh_fast(acc[2] * S.z + T.z);
                float h3 = tanh_fast(acc[3] * S.w + T.w);
                uint2 pk; pk.x = pack2bf(h0, h1); pk.y = pack2bf(h2, h3);
                *(uint2*)&hm[c][t * 16 + 4 * g] = pk;
            }
        }
        // root K-step s = mi+1 from hm slab
        {
            bf16x8 bfrag = *(const bf16x8*)&hm[c][g * 8];
            #pragma unroll
            for (int t = 0; t < 4; ++t) {
                bf16x8 a = *(const bf16x8*)(wsFrag + (WSB_ROOT + t * 9 + mi + 1) * 512 + lane * 8);
                accR[t] = __builtin_amdgcn_mfma_f32_16x16x32_bf16(a, bfrag, accR[t], 0, 0, 0);
            }
        }
        // prefetch stage for mi+2 (triple buffer => no WAR with current reads)
        if (mi < 6) stage(mi + 2, (mi + 2) % 3);
    }

    // root BN+tanh -> hr
    #pragma unroll
    for (int t = 0; t < 4; ++t) {
        const int po = t * 16 + 4 * g;
        float4 S = *(const float4*)(Sr + po);
        float4 T = *(const float4*)(Tr + po);
        float h0 = tanh_fast(accR[t][0] * S.x + T.x);
        float h1 = tanh_fast(accR[t][1] * S.y + T.y);
        float h2 = tanh_fast(accR[t][2] * S.z + T.z);
        float h3 = tanh_fast(accR[t][3] * S.w + T.w);
        uint2 pk; pk.x = pack2bf(h0, h1); pk.y = pack2bf(h2, h3);
        *(uint2*)&hr[c][po] = pk;
    }

    // head: 2 K-steps over hr
    {
        f32x4 acc = {0.f, 0.f, 0.f, 0.f};
        #pragma unroll
        for (int s = 0; s < 2; ++s) {
            bf16x8 bfrag = *(const bf16x8*)&hr[c][s * 32 + g * 8];
            bf16x8 a = *(const bf16x8*)(wsFrag + (WSB_HEAD + s) * 512 + lane * 8);
            acc = __builtin_amdgcn_mfma_f32_16x16x32_bf16(a, bfrag, acc, 0, 0, 0);
        }
        float* op = out + (size_t)(rowbase + c) * 10 + 4 * g;
        if (g < 2) {
            float2 o1 = {acc[0] + bh[4 * g],     acc[1] + bh[4 * g + 1]};
            float2 o2 = {acc[2] + bh[4 * g + 2], acc[3] + bh[4 * g + 3]};
            *(float2*)op = o1;
            *(float2*)(op + 2) = o2;
        } else if (g == 2) {
            float2 o1 = {acc[0] + bh[8], acc[1] + bh[9]};
            *(float2*)op = o1;
        }
    }
}

extern "C" void kernel_launch(void* const* d_in, const int* in_sizes, int n_in,
                              void* d_out, int out_size, void* d_ws, size_t ws_size,
                              hipStream_t stream) {
    const float* x     = (const float*)d_in[0];
    const float* Wl    = (const float*)d_in[1];
    const float* bl    = (const float*)d_in[2];
    const float* gl    = (const float*)d_in[3];
    const float* betal = (const float*)d_in[4];
    const float* ml    = (const float*)d_in[5];
    const float* vl    = (const float*)d_in[6];
    const float* Wm    = (const float*)d_in[7];
    const float* bm    = (const float*)d_in[8];
    const float* gm    = (const float*)d_in[9];
    const float* betam = (const float*)d_in[10];
    const float* mm    = (const float*)d_in[11];
    const float* vm    = (const float*)d_in[12];
    const float* Wr    = (const float*)d_in[13];
    const float* br    = (const float*)d_in[14];
    const float* gr    = (const float*)d_in[15];
    const float* betar = (const float*)d_in[16];
    const float* mr    = (const float*)d_in[17];
    const float* vr    = (const float*)d_in[18];
    const float* Wh    = (const float*)d_in[19];
    const float* bh    = (const float*)d_in[20];
    float* out = (float*)d_out;

    unsigned short* wsFrag = (unsigned short*)d_ws;
    float* wsST = (float*)((char*)d_ws + WS_ST_BYTE_OFF);

    ontology_prep<<<N_FRAG_BLOCKS + 3, 64, 0, stream>>>(
        Wl, Wm, Wr, Wh, bl, gl, betal, ml, vl, bm, gm, betam, mm, vm,
        br, gr, betar, mr, vr, wsFrag, wsST);

    const int n = in_sizes[0] / 1168;   // 16384
    ontology_mfma<<<n / 16, 64, 0, stream>>>(x, wsFrag, wsST, bh, out);
}

// Round 5
// 34.210 us; speedup vs baseline: 1.7243x; 1.7243x over previous
//
#include <hip/hip_runtime.h>

typedef __attribute__((ext_vector_type(8))) short bf16x8;
typedef __attribute__((ext_vector_type(4))) float f32x4;

#define EPS 1e-5f

// ws layout: frag blocks (182 x 1KB bf16) then fp32 ST region
#define N_FRAG_BLOCKS 182
#define WSB_LEAF 0      // 64 blocks: leaf l
#define WSB_MID  64     // 80 blocks: (m*2+t)*5 + s
#define WSB_ROOT 144    // 36 blocks: t*9 + s
#define WSB_HEAD 180    // 2 blocks: s
#define ST_SL 0
#define ST_TL 1024
#define ST_SM 2048
#define ST_TM 2304
#define ST_SR 2560
#define ST_TR 2624
#define WS_ST_BYTE_OFF (N_FRAG_BLOCKS * 1024)

__device__ __forceinline__ unsigned short f2bf(float f) {  // RNE float->bf16
    unsigned u = __float_as_uint(f);
    unsigned r = u + 0x7fffu + ((u >> 16) & 1u);
    return (unsigned short)(r >> 16);
}

__device__ __forceinline__ unsigned pack2bf(float a, float b) {
    return (unsigned)f2bf(a) | ((unsigned)f2bf(b) << 16);
}

__device__ __forceinline__ bf16x8 pack8(float4 a, float4 b) {
    union { unsigned u[4]; bf16x8 v; } r;
    r.u[0] = pack2bf(a.x, a.y); r.u[1] = pack2bf(a.z, a.w);
    r.u[2] = pack2bf(b.x, b.y); r.u[3] = pack2bf(b.z, b.w);
    return r.v;
}

__device__ __forceinline__ float tanh_fast(float x) {
    float e = __expf(2.0f * x);
    return 1.0f - 2.0f / (e + 1.0f);
}

// ---------------- prep: fragment-ordered bf16 weights + folded BN ----------
__global__ void ontology_prep(
    const float* __restrict__ Wl, const float* __restrict__ Wm,
    const float* __restrict__ Wr, const float* __restrict__ Wh,
    const float* __restrict__ bl, const float* __restrict__ gl,
    const float* __restrict__ betal, const float* __restrict__ ml,
    const float* __restrict__ vl,
    const float* __restrict__ bm, const float* __restrict__ gm,
    const float* __restrict__ betam, const float* __restrict__ mm,
    const float* __restrict__ vm,
    const float* __restrict__ br, const float* __restrict__ gr,
    const float* __restrict__ betar, const float* __restrict__ mr,
    const float* __restrict__ vr,
    unsigned short* __restrict__ wsFrag, float* __restrict__ wsST)
{
    const int b = blockIdx.x;
    const int t = threadIdx.x;
    if (b < N_FRAG_BLOCKS) {
        // A'-frag layout (transposed weights): lane t holds A'[row=t&15][k=(t>>4)*8+i]
        const int row = t & 15, g = t >> 4;
        unsigned short vals[8];
        #pragma unroll
        for (int i = 0; i < 8; ++i) {
            const int k = g * 8 + i;
            float v = 0.f;
            if (b < 64) {                       // leaf l: pair-packed K
                const int l = b;
                if ((l & 1) == 0) { if (k < 16)  v = Wl[l * 256 + k * 16 + row]; }
                else              { if (k >= 16) v = Wl[l * 256 + (k - 16) * 16 + row]; }
            } else if (b < 144) {               // mid
                const int idx = b - 64, m = idx / 10, rem = idx % 10;
                const int tt = rem / 5, s = rem % 5;
                const int krow = s * 32 + k;
                if (krow < 144) v = Wm[m * 4608 + krow * 32 + tt * 16 + row];
            } else if (b < 180) {               // root
                const int idx = b - 144, tt = idx / 9, s = idx % 9;
                if (s == 0) { if (k < 16) v = Wr[k * 64 + tt * 16 + row]; }
                else { const int krow = 16 + (s - 1) * 32 + k;
                       v = Wr[krow * 64 + tt * 16 + row]; }
            } else {                            // head
                const int s = b - 180, krow = s * 32 + k;
                if (row < 10) v = Wh[krow * 10 + row];
            }
            vals[i] = f2bf(v);
        }
        #pragma unroll
        for (int i = 0; i < 8; ++i) wsFrag[b * 512 + t * 8 + i] = vals[i];
    } else if (b == N_FRAG_BLOCKS) {            // leaf ST (1024)
        for (int i = 0; i < 16; ++i) {
            const int id = t + 64 * i;
            const float S = gl[id] * rsqrtf(vl[id] + EPS);
            wsST[ST_SL + id] = S;
            wsST[ST_TL + id] = (bl[id] - ml[id]) * S + betal[id];
        }
    } else if (b == N_FRAG_BLOCKS + 1) {        // mid ST (256)
        for (int i = 0; i < 4; ++i) {
            const int id = t + 64 * i;
            const float S = gm[id] * rsqrtf(vm[id] + EPS);
            wsST[ST_SM + id] = S;
            wsST[ST_TM + id] = (bm[id] - mm[id]) * S + betam[id];
        }
    } else {                                     // root ST (64)
        const int id = t;
        const float S = gr[id] * rsqrtf(vr[id] + EPS);
        wsST[ST_SR + id] = S;
        wsST[ST_TR + id] = (br[id] - mr[id]) * S + betar[id];
    }
}

// ---------------- main fused MFMA kernel -----------------------------------
// Block = 256 thr = 4 waves = one 16-row M-tile. Wave w handles mids 2w,2w+1
// (+16 leaves), root col-tile w. ALL x loads for both phases are issued at
// kernel top into VGPRs (72 regs) so the full x stream is in flight early.
// Outputs transposed (feat rows x sample cols); lane (c=sample, g=group).
// 2 barriers total.
__global__ __launch_bounds__(256, 4) void ontology_mfma(
    const float* __restrict__ x,
    const unsigned short* __restrict__ wsFrag,
    const float* __restrict__ wsST,
    const float* __restrict__ bh,
    float* __restrict__ out)
{
    // strides in bf16: 168 (=21*8), 264 (=33*8), 72 (=9*8): 16B-granule
    // stride odd => b128 reads / b64 writes at worst 2-way (free).
    __shared__ __align__(16) unsigned short mid_in[4][16][168];  // per-wave
    __shared__ __align__(16) unsigned short hm[16][264];         // shared
    unsigned short (*hr)[72] = (unsigned short (*)[72])&mid_in[0][0][0]; // alias, post-barrier-1

    const int w    = threadIdx.x >> 6;
    const int lane = threadIdx.x & 63;
    const int c    = lane & 15;       // sample within tile
    const int g    = lane >> 4;       // k/feat group
    const int rowbase = blockIdx.x * 16;
    const float* xrow = x + (size_t)(rowbase + c) * 1168;
    const int m0 = 2 * w, m1 = 2 * w + 1;

    // ---------- issue ALL x loads up front (both phases + root slice) ------
    float4 xr_a = *(const float4*)(xrow + 1152 + (g & 1) * 8);
    float4 xr_b = *(const float4*)(xrow + 1152 + (g & 1) * 8 + 4);
    float4 xm4_0 = *(const float4*)(xrow + 1024 + m0 * 16 + 4 * g);
    float4 xm4_1 = *(const float4*)(xrow + 1024 + m1 * 16 + 4 * g);
    float4 xp0[4][2], xp1[4][2];
    #pragma unroll
    for (int p = 0; p < 4; ++p) {
        const float* a0 = xrow + (m0 * 4 + p) * 32 + g * 8;
        xp0[p][0] = *(const float4*)a0;
        xp0[p][1] = *(const float4*)(a0 + 4);
    }
    #pragma unroll
    for (int p = 0; p < 4; ++p) {
        const float* a1 = xrow + (m1 * 4 + p) * 32 + g * 8;
        xp1[p][0] = *(const float4*)a1;
        xp1[p][1] = *(const float4*)(a1 + 4);
    }

    const float* Sl = wsST + ST_SL; const float* Tl = wsST + ST_TL;
    const float* Sm = wsST + ST_SM; const float* Tm = wsST + ST_TM;
    const float* Sr = wsST + ST_SR; const float* Tr = wsST + ST_TR;

    // zero pad-K columns 144..159 of this wave's mid_in (written once)
    {
        uint2 z; z.x = 0u; z.y = 0u;
        *(uint2*)&mid_in[w][c][144 + 4 * g] = z;
    }

    // root accumulator; K-step s=0 from x[1152..1168] (A' rows k>=16 are 0)
    f32x4 accR;
    {
        bf16x8 bfrag = pack8(xr_a, xr_b);
        bf16x8 a = *(const bf16x8*)(wsFrag + (WSB_ROOT + w * 9) * 512 + lane * 8);
        f32x4 zz = {0.f, 0.f, 0.f, 0.f};
        accR = __builtin_amdgcn_mfma_f32_16x16x32_bf16(a, bfrag, zz, 0, 0, 0);
    }

    // ---------- one phase: leaves + mid, consuming preloaded x -------------
    auto phase = [&](int mi, const float4& xm4, const float4 xp[4][2]) {
        // xm (cols 0..15) -> mid_in
        {
            uint2 pm; pm.x = pack2bf(xm4.x, xm4.y); pm.y = pack2bf(xm4.z, xm4.w);
            *(uint2*)&mid_in[w][c][4 * g] = pm;
        }
        // 4 leaf-pairs -> 8 leaves, outputs into mid_in cols 16..143
        #pragma unroll
        for (int p = 0; p < 4; ++p) {
            bf16x8 bfrag = pack8(xp[p][0], xp[p][1]);
            #pragma unroll
            for (int e = 0; e < 2; ++e) {
                const int leaf = mi * 8 + p * 2 + e;
                bf16x8 afrag = *(const bf16x8*)(wsFrag + (WSB_LEAF + leaf) * 512 + lane * 8);
                f32x4 zz = {0.f, 0.f, 0.f, 0.f};
                f32x4 acc = __builtin_amdgcn_mfma_f32_16x16x32_bf16(afrag, bfrag, zz, 0, 0, 0);
                float4 S = *(const float4*)(Sl + leaf * 16 + 4 * g);
                float4 T = *(const float4*)(Tl + leaf * 16 + 4 * g);
                float h0 = tanh_fast(acc[0] * S.x + T.x);
                float h1 = tanh_fast(acc[1] * S.y + T.y);
                float h2 = tanh_fast(acc[2] * S.z + T.z);
                float h3 = tanh_fast(acc[3] * S.w + T.w);
                uint2 pk; pk.x = pack2bf(h0, h1); pk.y = pack2bf(h2, h3);
                *(uint2*)&mid_in[w][c][16 + (p * 2 + e) * 16 + 4 * g] = pk;
            }
        }
        // mid mi: 2 col-tiles x 5 K-steps
        {
            f32x4 acc0 = {0.f, 0.f, 0.f, 0.f};
            f32x4 acc1 = {0.f, 0.f, 0.f, 0.f};
            const unsigned short* fb = wsFrag + (WSB_MID + mi * 10) * 512 + lane * 8;
            #pragma unroll
            for (int s = 0; s < 5; ++s) {
                bf16x8 bfrag = *(const bf16x8*)&mid_in[w][c][s * 32 + g * 8];
                bf16x8 a0 = *(const bf16x8*)(fb + s * 512);
                bf16x8 a1 = *(const bf16x8*)(fb + (5 + s) * 512);
                acc0 = __builtin_amdgcn_mfma_f32_16x16x32_bf16(a0, bfrag, acc0, 0, 0, 0);
                acc1 = __builtin_amdgcn_mfma_f32_16x16x32_bf16(a1, bfrag, acc1, 0, 0, 0);
            }
            #pragma unroll
            for (int t = 0; t < 2; ++t) {
                f32x4 acc = t ? acc1 : acc0;
                const int po = mi * 32 + t * 16 + 4 * g;
                float4 S = *(const float4*)(Sm + po);
                float4 T = *(const float4*)(Tm + po);
                float h0 = tanh_fast(acc[0] * S.x + T.x);
                float h1 = tanh_fast(acc[1] * S.y + T.y);
                float h2 = tanh_fast(acc[2] * S.z + T.z);
                float h3 = tanh_fast(acc[3] * S.w + T.w);
                uint2 pk; pk.x = pack2bf(h0, h1); pk.y = pack2bf(h2, h3);
                *(uint2*)&hm[c][po] = pk;
            }
        }
    };

    phase(m0, xm4_0, xp0);
    phase(m1, xm4_1, xp1);

    __syncthreads();   // barrier 1: hm complete (all waves)

    // root col-tile w: K-steps s=1..8 over hm
    {
        const unsigned short* fb = wsFrag + (WSB_ROOT + w * 9) * 512 + lane * 8;
        #pragma unroll
        for (int s = 1; s <= 8; ++s) {
            bf16x8 bfrag = *(const bf16x8*)&hm[c][(s - 1) * 32 + g * 8];
            bf16x8 a0 = *(const bf16x8*)(fb + s * 512);
            accR = __builtin_amdgcn_mfma_f32_16x16x32_bf16(a0, bfrag, accR, 0, 0, 0);
        }
        const int po = w * 16 + 4 * g;
        float4 S = *(const float4*)(Sr + po);
        float4 T = *(const float4*)(Tr + po);
        float h0 = tanh_fast(accR[0] * S.x + T.x);
        float h1 = tanh_fast(accR[1] * S.y + T.y);
        float h2 = tanh_fast(accR[2] * S.z + T.z);
        float h3 = tanh_fast(accR[3] * S.w + T.w);
        uint2 pk; pk.x = pack2bf(h0, h1); pk.y = pack2bf(h2, h3);
        *(uint2*)&hr[c][po] = pk;
    }
    __syncthreads();   // barrier 2: hr complete

    // head (wave 0 only): tasks in rows, samples in cols
    if (w == 0) {
        f32x4 acc = {0.f, 0.f, 0.f, 0.f};
        #pragma unroll
        for (int s = 0; s < 2; ++s) {
            bf16x8 bfrag = *(const bf16x8*)&hr[c][s * 32 + g * 8];
            bf16x8 a0 = *(const bf16x8*)(wsFrag + (WSB_HEAD + s) * 512 + lane * 8);
            acc = __builtin_amdgcn_mfma_f32_16x16x32_bf16(a0, bfrag, acc, 0, 0, 0);
        }
        float* op = out + (size_t)(rowbase + c) * 10 + 4 * g;
        if (g < 2) {
            float2 o1 = {acc[0] + bh[4 * g],     acc[1] + bh[4 * g + 1]};
            float2 o2 = {acc[2] + bh[4 * g + 2], acc[3] + bh[4 * g + 3]};
            *(float2*)op = o1;
            *(float2*)(op + 2) = o2;
        } else if (g == 2) {
            float2 o1 = {acc[0] + bh[8], acc[1] + bh[9]};
            *(float2*)op = o1;
        }
    }
}

extern "C" void kernel_launch(void* const* d_in, const int* in_sizes, int n_in,
                              void* d_out, int out_size, void* d_ws, size_t ws_size,
                              hipStream_t stream) {
    const float* x     = (const float*)d_in[0];
    const float* Wl    = (const float*)d_in[1];
    const float* bl    = (const float*)d_in[2];
    const float* gl    = (const float*)d_in[3];
    const float* betal = (const float*)d_in[4];
    const float* ml    = (const float*)d_in[5];
    const float* vl    = (const float*)d_in[6];
    const float* Wm    = (const float*)d_in[7];
    const float* bm    = (const float*)d_in[8];
    const float* gm    = (const float*)d_in[9];
    const float* betam = (const float*)d_in[10];
    const float* mm    = (const float*)d_in[11];
    const float* vm    = (const float*)d_in[12];
    const float* Wr    = (const float*)d_in[13];
    const float* br    = (const float*)d_in[14];
    const float* gr    = (const float*)d_in[15];
    const float* betar = (const float*)d_in[16];
    const float* mr    = (const float*)d_in[17];
    const float* vr    = (const float*)d_in[18];
    const float* Wh    = (const float*)d_in[19];
    const float* bh    = (const float*)d_in[20];
    float* out = (float*)d_out;

    unsigned short* wsFrag = (unsigned short*)d_ws;
    float* wsST = (float*)((char*)d_ws + WS_ST_BYTE_OFF);

    ontology_prep<<<N_FRAG_BLOCKS + 3, 64, 0, stream>>>(
        Wl, Wm, Wr, Wh, bl, gl, betal, ml, vl, bm, gm, betam, mm, vm,
        br, gr, betar, mr, vr, wsFrag, wsST);

    const int n = in_sizes[0] / 1168;   // 16384
    ontology_mfma<<<n / 16, 256, 0, stream>>>(x, wsFrag, wsST, bh, out);
}